// Round 20
// baseline (301.826 us; speedup 1.0000x reference)
//
#include <hip/hip_runtime.h>
#include <math.h>

#define N_TOK 2000
#define NH 8
#define HD 32
#define SCALE 25.0f
#define SIM_TH 0.75f
#define EPSF 1e-8f
#define NSLOT 8   // ceil(2000/256)
#define NTAIL 208 // valid lanes in slot 7: 2000 - 7*256
#define SPAD 2048 // padded s_attn stride

typedef _Float16 half2_t __attribute__((ext_vector_type(2)));

__device__ __forceinline__ unsigned rflu(unsigned u) {
  return (unsigned)__builtin_amdgcn_readfirstlane((int)u);
}
__device__ __forceinline__ half2_t u2h(unsigned u) {
  return __builtin_bit_cast(half2_t, u);
}
__device__ __forceinline__ unsigned h2u(half2_t h) {
  return __builtin_bit_cast(unsigned, h);
}

// f32 += f16x2 . f16x2 (v_dot2_f32_f16; products exact, fp32 accumulate)
__device__ __forceinline__ float fdot2f(unsigned a, unsigned b, float c) {
#if __has_builtin(__builtin_amdgcn_fdot2)
  return __builtin_amdgcn_fdot2(u2h(a), u2h(b), c, false);
#else
  const half2_t ha = u2h(a), hb = u2h(b);
  return c + (float)ha.x * (float)hb.x + (float)ha.y * (float)hb.y;
#endif
}

__device__ __forceinline__ float block_max256(float v, float* red) {
#pragma unroll
  for (int off = 32; off > 0; off >>= 1) v = fmaxf(v, __shfl_xor(v, off, 64));
  __syncthreads();
  if ((threadIdx.x & 63) == 0) red[threadIdx.x >> 6] = v;
  __syncthreads();
  return fmaxf(fmaxf(red[0], red[1]), fmaxf(red[2], red[3]));
}
__device__ __forceinline__ float block_sum256(float v, float* red) {
#pragma unroll
  for (int off = 32; off > 0; off >>= 1) v += __shfl_xor(v, off, 64);
  __syncthreads();
  if ((threadIdx.x & 63) == 0) red[threadIdx.x >> 6] = v;
  __syncthreads();
  return (red[0] + red[1]) + (red[2] + red[3]);
}
// one packed block reduction for 4 sums (2 syncs total instead of 8)
__device__ __forceinline__ void block_sum4(float* v, float* red16) {
#pragma unroll
  for (int off = 32; off > 0; off >>= 1) {
#pragma unroll
    for (int q = 0; q < 4; q++) v[q] += __shfl_xor(v[q], off, 64);
  }
  __syncthreads();
  const int wid = threadIdx.x >> 6;
  if ((threadIdx.x & 63) == 0) {
#pragma unroll
    for (int q = 0; q < 4; q++) red16[wid * 4 + q] = v[q];
  }
  __syncthreads();
#pragma unroll
  for (int q = 0; q < 4; q++) {
    v[q] = (red16[q] + red16[4 + q]) + (red16[8 + q] + red16[12 + q]);
  }
}

// load a query pair's packed-f16 row into uniform uints (SGPRs)
#define LOAD_QPAIR(BUF)                                                   \
  {                                                                       \
    const uint4* __restrict__ qb = (const uint4*)(BUF) + (size_t)h * 4 * N_TOK; \
    _Pragma("unroll") for (int gg = 0; gg < 4; gg++) {                    \
      const uint4 a0 = qb[gg * N_TOK + i0];                               \
      const uint4 a1 = qb[gg * N_TOK + i1];                               \
      qp0[4 * gg + 0] = rflu(a0.x); qp0[4 * gg + 1] = rflu(a0.y);         \
      qp0[4 * gg + 2] = rflu(a0.z); qp0[4 * gg + 3] = rflu(a0.w);         \
      qp1[4 * gg + 0] = rflu(a1.x); qp1[4 * gg + 1] = rflu(a1.y);         \
      qp1[4 * gg + 2] = rflu(a1.z); qp1[4 * gg + 3] = rflu(a1.w);         \
    }                                                                     \
  }
// same, but into per-lane VGPRs (SGPR file is full at 112)
#define LOAD_QPAIR_V(BUF)                                                 \
  {                                                                       \
    const uint4* __restrict__ qb = (const uint4*)(BUF) + (size_t)h * 4 * N_TOK; \
    _Pragma("unroll") for (int gg = 0; gg < 4; gg++) {                    \
      const uint4 a0 = qb[gg * N_TOK + i0];                               \
      const uint4 a1 = qb[gg * N_TOK + i1];                               \
      qv0[4 * gg + 0] = a0.x; qv0[4 * gg + 1] = a0.y;                     \
      qv0[4 * gg + 2] = a0.z; qv0[4 * gg + 3] = a0.w;                     \
      qv1[4 * gg + 0] = a1.x; qv1[4 * gg + 1] = a1.y;                     \
      qv1[4 * gg + 2] = a1.z; qv1[4 * gg + 3] = a1.w;                     \
    }                                                                     \
  }

// ---------------------------------------------------------------------------
// Kernel 0: pack W fp32 [256][768] into f16 pair-quads Wq[k/8][768].
// grid = (96, 2), block = 256
// ---------------------------------------------------------------------------
__global__ __launch_bounds__(256) void wpack_kernel(
    const float* __restrict__ W_cls, const float* __restrict__ W_reg,
    unsigned* __restrict__ Wp_cls, unsigned* __restrict__ Wp_reg) {
  const int idx = blockIdx.x * 256 + threadIdx.x;
  const int kq = idx / 768, c = idx % 768;
  const float* __restrict__ W = blockIdx.y ? W_reg : W_cls;
  uint4* __restrict__ Wq = (uint4*)(blockIdx.y ? Wp_reg : Wp_cls);
  uint4 o;
  o.x = h2u((half2_t){(_Float16)W[(8 * kq + 0) * 768 + c],
                      (_Float16)W[(8 * kq + 1) * 768 + c]});
  o.y = h2u((half2_t){(_Float16)W[(8 * kq + 2) * 768 + c],
                      (_Float16)W[(8 * kq + 3) * 768 + c]});
  o.z = h2u((half2_t){(_Float16)W[(8 * kq + 4) * 768 + c],
                      (_Float16)W[(8 * kq + 5) * 768 + c]});
  o.w = h2u((half2_t){(_Float16)W[(8 * kq + 6) * 768 + c],
                      (_Float16)W[(8 * kq + 7) * 768 + c]});
  Wq[idx] = o;
}

// ---------------------------------------------------------------------------
// Kernel 1: QKV projection via f16 W + fdot2, 4 rows/block.
// grid = (500, 2), block = 256
// ---------------------------------------------------------------------------
__global__ __launch_bounds__(256) void qkv_norm_kernel(
    const float* __restrict__ x_cls, const float* __restrict__ x_reg,
    const unsigned* __restrict__ Wp_cls, const unsigned* __restrict__ Wp_reg,
    _Float16* __restrict__ qc_h, _Float16* __restrict__ qr_h,
    _Float16* __restrict__ kc_h, _Float16* __restrict__ kr_h,
    _Float16* __restrict__ vn_h, float* __restrict__ v_rm,
    _Float16* __restrict__ v_h) {
  __shared__ unsigned xs_p[4][128];
  __shared__ float res[4][768];
  __shared__ float inv_norm[96];

  const int n0 = blockIdx.x * 4;
  const int which = blockIdx.y;
  const int tid = threadIdx.x;
  const float* __restrict__ x = which ? x_reg : x_cls;
  const uint4* __restrict__ Wq = (const uint4*)(which ? Wp_reg : Wp_cls);

  if (tid < 128) {
#pragma unroll
    for (int r = 0; r < 4; r++) {
      const float2 xv = ((const float2*)x)[(size_t)(n0 + r) * 128 + tid];
      xs_p[r][tid] = h2u((half2_t){(_Float16)xv.x, (_Float16)xv.y});
    }
  }
  __syncthreads();

  float acc[4][3];
#pragma unroll
  for (int r = 0; r < 4; r++) acc[r][0] = acc[r][1] = acc[r][2] = 0.f;

#pragma unroll 2
  for (int kq = 0; kq < 32; kq++) {
    const uint4 w0 = Wq[kq * 768 + tid];
    const uint4 w1 = Wq[kq * 768 + tid + 256];
    const uint4 w2 = Wq[kq * 768 + tid + 512];
#pragma unroll
    for (int r = 0; r < 4; r++) {
      const uint4 xp = *(const uint4*)&xs_p[r][kq * 4];
      acc[r][0] = fdot2f(w0.x, xp.x, acc[r][0]);
      acc[r][0] = fdot2f(w0.y, xp.y, acc[r][0]);
      acc[r][0] = fdot2f(w0.z, xp.z, acc[r][0]);
      acc[r][0] = fdot2f(w0.w, xp.w, acc[r][0]);
      acc[r][1] = fdot2f(w1.x, xp.x, acc[r][1]);
      acc[r][1] = fdot2f(w1.y, xp.y, acc[r][1]);
      acc[r][1] = fdot2f(w1.z, xp.z, acc[r][1]);
      acc[r][1] = fdot2f(w1.w, xp.w, acc[r][1]);
      acc[r][2] = fdot2f(w2.x, xp.x, acc[r][2]);
      acc[r][2] = fdot2f(w2.y, xp.y, acc[r][2]);
      acc[r][2] = fdot2f(w2.z, xp.z, acc[r][2]);
      acc[r][2] = fdot2f(w2.w, xp.w, acc[r][2]);
    }
  }
#pragma unroll
  for (int r = 0; r < 4; r++) {
    res[r][tid] = acc[r][0];
    res[r][tid + 256] = acc[r][1];
    res[r][tid + 512] = acc[r][2];
  }
  __syncthreads();

  if (tid < 96) {
    const int r = tid / 24, grp = tid % 24;
    float ss = 0.f;
#pragma unroll
    for (int d = 0; d < HD; d++) {
      const float v = res[r][grp * 32 + d];
      ss += v * v;
    }
    inv_norm[tid] = 1.0f / (sqrtf(ss) + EPSF);
  }
  __syncthreads();

#pragma unroll
  for (int j = 0; j < 3; j++) {
    const int c = tid + j * 256;
    const int qkv = c >> 8, grp = c >> 5;
    const int h = grp & 7, d = c & 31;
    const int gg = d >> 3, dd = d & 7;
#pragma unroll
    for (int r = 0; r < 4; r++) {
      const int n = n0 + r;
      const float val = res[r][c];
      const float nval = val * inv_norm[r * 24 + grp];
      const size_t fi = ((size_t)(h * 4 + gg) * N_TOK + n) * 8 + dd;
      if (qkv == 0) {
        (which ? qr_h : qc_h)[fi] = (_Float16)nval;
      } else if (qkv == 1) {
        (which ? kr_h : kc_h)[fi] = (_Float16)nval;
      } else if (which == 0) {
        v_rm[(h * N_TOK + n) * HD + d] = val;
        vn_h[fi] = (_Float16)nval;
        v_h[((size_t)h * N_TOK + n) * HD + d] = (_Float16)val;
      }
    }
  }
}

// ---------------------------------------------------------------------------
// Kernel 2: r19 structure with the C and R score sweeps MERGED into one
// m-loop reading both K planes (two independent address streams the compiler
// cannot collapse): 8 uint4 loads + 64 fdot2 per iteration. The reg q-pair
// lives in VGPRs (SGPR file full). #pragma unroll 1 on the merged loop
// bounds register pressure (r6 lesson). V phase unchanged (reuses SGPR q).
// grid = 1000, block = 256
// ---------------------------------------------------------------------------
__global__ __launch_bounds__(256) void attn20_kernel(
    const _Float16* __restrict__ qc_h, const _Float16* __restrict__ qr_h,
    const _Float16* __restrict__ kc_h, const _Float16* __restrict__ kr_h,
    const _Float16* __restrict__ vn_h, const float* __restrict__ v_rm,
    const _Float16* __restrict__ v_h,
    float* __restrict__ out_x, float* __restrict__ out_sim) {
  __shared__ float s_attn[2][SPAD];  // 16 KB; tails stay 0 for PV
  __shared__ float s_union[4608];    // 18.4 KB: er[2][2000] / part (str 17)
  __shared__ float red[16];

  float* __restrict__ s_er = s_union;
  float* __restrict__ part = s_union;  // [64 slices][4 g2] units of 17 floats

  const int tid = threadIdx.x;
  const int i0 = blockIdx.x * 2;
  const int i1 = i0 + 1;
  const int bs = (i0 / 10) * 10;  // i0 even -> i0,i1 share the same decade

  float sim0[NSLOT], sim1[NSLOT], raw0[NSLOT], raw1[NSLOT];
#pragma unroll
  for (int t = 0; t < NSLOT; t++) {
    sim0[t] = 0.f; sim1[t] = 0.f; raw0[t] = 0.f; raw1[t] = 0.f;
  }
  if (tid < SPAD - N_TOK) {
    s_attn[0][N_TOK + tid] = 0.f;
    s_attn[1][N_TOK + tid] = 0.f;
  }
  __syncthreads();

  unsigned qp0[16], qp1[16];  // cls / vn q pairs, wave-uniform -> SGPR
  unsigned qv0[16], qv1[16];  // reg q pair -> VGPRs

  // pipelined single-stream sweep (used for the V phase)
  auto sweep = [&](const uint4* __restrict__ kt4, auto&& emit) {
    uint4 ka[4], kb[4];
#pragma unroll
    for (int g_ = 0; g_ < 4; g_++) ka[g_] = kt4[g_ * N_TOK + tid];  // t=0
#pragma unroll
    for (int t = 0; t < NSLOT; t++) {
      if (t < NSLOT - 1) {  // prefetch t+1 while computing t
        const int m1 = tid + 256 * (t + 1);
        const bool v1 = (t + 1 < 7) || (tid < NTAIL);
        const int mc1 = v1 ? m1 : (N_TOK - 1);
#pragma unroll
        for (int g_ = 0; g_ < 4; g_++) kb[g_] = kt4[g_ * N_TOK + mc1];
      }
      float d0 = 0.f, d1 = 0.f;
#pragma unroll
      for (int g_ = 0; g_ < 4; g_++) {
        d0 = fdot2f(ka[g_].x, qp0[4 * g_ + 0], d0);
        d0 = fdot2f(ka[g_].y, qp0[4 * g_ + 1], d0);
        d0 = fdot2f(ka[g_].z, qp0[4 * g_ + 2], d0);
        d0 = fdot2f(ka[g_].w, qp0[4 * g_ + 3], d0);
        d1 = fdot2f(ka[g_].x, qp1[4 * g_ + 0], d1);
        d1 = fdot2f(ka[g_].y, qp1[4 * g_ + 1], d1);
        d1 = fdot2f(ka[g_].z, qp1[4 * g_ + 2], d1);
        d1 = fdot2f(ka[g_].w, qp1[4 * g_ + 3], d1);
      }
      emit(t, d0, d1);
#pragma unroll
      for (int g_ = 0; g_ < 4; g_++) ka[g_] = kb[g_];
    }
  };

  for (int hh = 0; hh < NH; hh++) {
    const int h = (blockIdx.x + hh) & 7;  // XCD-local head schedule

    float sums[4] = {0.f, 0.f, 0.f, 0.f};  // ls0, ls1, lr0, lr1

    // ===== merged C+R sweep: two independent K streams per iteration =====
    LOAD_QPAIR(qc_h);
    LOAD_QPAIR_V(qr_h);
    {
      const uint4* __restrict__ kc4 =
          (const uint4*)kc_h + (size_t)h * 4 * N_TOK;
      const uint4* __restrict__ kr4 =
          (const uint4*)kr_h + (size_t)h * 4 * N_TOK;
#pragma unroll 1
      for (int t = 0; t < NSLOT; t++) {
        const int m = tid + 256 * t;
        const bool valid = (t < 7) || (tid < NTAIL);
        const int mc = valid ? m : (N_TOK - 1);
        uint4 ac[4], ar[4];
#pragma unroll
        for (int g_ = 0; g_ < 4; g_++) ac[g_] = kc4[g_ * N_TOK + mc];
#pragma unroll
        for (int g_ = 0; g_ < 4; g_++) ar[g_] = kr4[g_ * N_TOK + mc];
        float dc0 = 0.f, dc1 = 0.f, dr0 = 0.f, dr1 = 0.f;
#pragma unroll
        for (int g_ = 0; g_ < 4; g_++) {
          dc0 = fdot2f(ac[g_].x, qp0[4 * g_ + 0], dc0);
          dc0 = fdot2f(ac[g_].y, qp0[4 * g_ + 1], dc0);
          dc0 = fdot2f(ac[g_].z, qp0[4 * g_ + 2], dc0);
          dc0 = fdot2f(ac[g_].w, qp0[4 * g_ + 3], dc0);
          dc1 = fdot2f(ac[g_].x, qp1[4 * g_ + 0], dc1);
          dc1 = fdot2f(ac[g_].y, qp1[4 * g_ + 1], dc1);
          dc1 = fdot2f(ac[g_].z, qp1[4 * g_ + 2], dc1);
          dc1 = fdot2f(ac[g_].w, qp1[4 * g_ + 3], dc1);
          dr0 = fdot2f(ar[g_].x, qv0[4 * g_ + 0], dr0);
          dr0 = fdot2f(ar[g_].y, qv0[4 * g_ + 1], dr0);
          dr0 = fdot2f(ar[g_].z, qv0[4 * g_ + 2], dr0);
          dr0 = fdot2f(ar[g_].w, qv0[4 * g_ + 3], dr0);
          dr1 = fdot2f(ar[g_].x, qv1[4 * g_ + 0], dr1);
          dr1 = fdot2f(ar[g_].y, qv1[4 * g_ + 1], dr1);
          dr1 = fdot2f(ar[g_].z, qv1[4 * g_ + 2], dr1);
          dr1 = fdot2f(ar[g_].w, qv1[4 * g_ + 3], dr1);
        }
        const float ec0 = valid ? __expf(dc0 * SCALE - SCALE) : 0.f;
        const float ec1 = valid ? __expf(dc1 * SCALE - SCALE) : 0.f;
        const float er0 = valid ? __expf(dr0 * SCALE - SCALE) : 0.f;
        const float er1 = valid ? __expf(dr1 * SCALE - SCALE) : 0.f;
        sums[0] += ec0; sums[1] += ec1;
        sums[2] += er0; sums[3] += er1;
        if (valid) {
          s_attn[0][m] = ec0;
          s_attn[1][m] = ec1;
          s_er[m] = er0;
          s_er[N_TOK + m] = er1;
        }
      }
    }

    // ===== ONE packed reduction for all 4 softmax sums =====
    block_sum4(sums, red);
    const float n0c = 0.5f / sums[0], n1c = 0.5f / sums[1];
    const float n0r = 0.5f / sums[2], n1r = 0.5f / sums[3];

    // ===== combine, mask, sim += =====
#pragma unroll
    for (int t = 0; t < NSLOT; t++) {
      const int m = tid + 256 * t;
      if ((t < 7) || (tid < NTAIL)) {
        float a0 = s_attn[0][m] * n0c + s_er[m] * n0r;
        float a1 = s_attn[1][m] * n1c + s_er[N_TOK + m] * n1r;
        if (m >= bs && m < bs + 9) {
          if (m != i0) a0 = 0.f;
          if (m != i1) a1 = 0.f;
        }
        s_attn[0][m] = a0;
        s_attn[1][m] = a1;
        sim0[t] += a0;
        sim1[t] += a1;
      }
    }

    // ===== phase V: vn cosine -> raw += (SGPR q slots free again) =====
    LOAD_QPAIR(vn_h);
    sweep((const uint4*)vn_h + (size_t)h * 4 * N_TOK,
          [&](int t, float d0, float d1) {
            const bool valid = (t < 7) || (tid < NTAIL);
            if (valid) { raw0[t] += d0; raw1[t] += d1; }
          });
    __syncthreads();  // s_attn final; s_er reads done -> part may reuse

    // ===== attn @ V : f16 V row-major, one uint4 = 8 d per load =====
    {
      const int g2 = tid & 3;        // d-group of 8
      const int slice = tid >> 2;    // 64 slices x 32 m
      const int m0 = slice * 32;
      float acc0[8], acc1[8];
#pragma unroll
      for (int e = 0; e < 8; e++) { acc0[e] = 0.f; acc1[e] = 0.f; }
      const _Float16* __restrict__ vb =
          v_h + (size_t)h * N_TOK * HD + g2 * 8;
#pragma unroll 2
      for (int jj = 0; jj < 8; jj++) {
        const int m = m0 + 4 * ((jj + slice) & 7);  // rotated: <=2-way LDS
        const float4 av0 = *(const float4*)&s_attn[0][m];
        const float4 av1 = *(const float4*)&s_attn[1][m];
        // m can reach 2047; av=0 there. v_h overrun (<=1.5k elems) lands in
        // the adjacent f16 plane (finite values; x0 = 0).
        uint4 vv[4];
#pragma unroll
        for (int mm = 0; mm < 4; mm++) {
          vv[mm] = *(const uint4*)(vb + (size_t)(m + mm) * HD);
        }
#pragma unroll
        for (int mm = 0; mm < 4; mm++) {
          const float a0 = ((const float*)&av0)[mm];
          const float a1 = ((const float*)&av1)[mm];
          const unsigned* vp = (const unsigned*)&vv[mm];
#pragma unroll
          for (int e = 0; e < 4; e++) {
            const half2_t hv = u2h(vp[e]);
            const float vx = (float)hv.x, vy = (float)hv.y;
            acc0[2 * e] += a0 * vx;
            acc0[2 * e + 1] += a0 * vy;
            acc1[2 * e] += a1 * vx;
            acc1[2 * e + 1] += a1 * vy;
          }
        }
      }
      __syncthreads();  // er reads in combine long done; part write safe
      float* pu = part + (size_t)(slice * 4 + g2) * 17;  // stride 17
#pragma unroll
      for (int e = 0; e < 8; e++) {
        pu[e] = acc0[e];
        pu[8 + e] = acc1[e];
      }
    }
    __syncthreads();
    if (tid < 64) {
      const int q = tid >> 5, d = tid & 31;
      const int g = d >> 3, e = d & 7;
      float s = 0.f;
#pragma unroll 8
      for (int sl = 0; sl < 64; sl++) {
        s += part[(size_t)(sl * 4 + g) * 17 + q * 8 + e];
      }
      const int irow = q ? i1 : i0;
      out_x[(size_t)irow * 512 + h * 32 + d] = s;
    } else if (tid >= 64 && tid < 128) {
      const int q = (tid - 64) >> 5, d = (tid - 64) & 31;
      const int irow = q ? i1 : i0;
      out_x[(size_t)irow * 512 + 256 + h * 32 + d] =
          v_rm[((size_t)h * N_TOK + irow) * HD + d];
    }
    __syncthreads();  // part reads done -> s_er reuse next head
  }

  // ===== sim_round2 epilogue, from registers =====
#pragma unroll
  for (int q = 0; q < 2; q++) {
    const int irow = q ? i1 : i0;
    float* __restrict__ sim = q ? sim1 : sim0;
    float* __restrict__ raw = q ? raw1 : raw0;

    float lm = -1e30f;
#pragma unroll
    for (int t = 0; t < NSLOT; t++) {
      if ((t < 7) || (tid < NTAIL)) lm = fmaxf(lm, sim[t] * 0.125f);
    }
    const float M = block_max256(lm, red);

    float ls = 0.f;
#pragma unroll
    for (int t = 0; t < NSLOT; t++) {
      const bool valid = (t < 7) || (tid < NTAIL);
      const float e = valid ? __expf(sim[t] * 0.125f - M) : 0.f;
      sim[t] = e;
      ls += e;
    }
    const float S = block_sum256(ls, red);
    const float invS = 1.0f / S;

    float lms = 0.f;
#pragma unroll
    for (int t = 0; t < NSLOT; t++) {
      const bool valid = (t < 7) || (tid < NTAIL);
      const float p = sim[t] * invS;
      const float mp = (valid && (raw[t] * 0.125f > SIM_TH)) ? p : 0.f;
      sim[t] = mp;
      lms += mp;
    }
    const float MS = block_sum256(lms, red);
    const float invMS = 1.0f / (MS + EPSF);

#pragma unroll
    for (int t = 0; t < NSLOT; t++) {
      const int m = tid + 256 * t;
      if ((t < 7) || (tid < NTAIL)) {
        out_sim[(size_t)irow * N_TOK + m] = sim[t] * invMS;
      }
    }
  }
}

// ---------------------------------------------------------------------------
extern "C" void kernel_launch(void* const* d_in, const int* in_sizes, int n_in,
                              void* d_out, int out_size, void* d_ws,
                              size_t ws_size, hipStream_t stream) {
  const float* x_cls = (const float*)d_in[0];
  const float* x_reg = (const float*)d_in[1];
  const float* W_cls = (const float*)d_in[2];
  const float* W_reg = (const float*)d_in[3];

  // ws layout: v_rm fp32, v_h f16 (NOT last: PV overrun must hit finite f16
  // data), then the score planes, then packed W.
  const size_t seg = (size_t)NH * N_TOK * HD;  // 512000 elements
  float* v_rm = (float*)d_ws;
  _Float16* v_h = (_Float16*)(v_rm + seg);
  _Float16* qc_h = v_h + seg;
  _Float16* qr_h = qc_h + seg;
  _Float16* kc_h = qr_h + seg;
  _Float16* kr_h = kc_h + seg;
  _Float16* vn_h = kr_h + seg;
  unsigned* Wp_cls = (unsigned*)(vn_h + seg);  // 98304 uints each
  unsigned* Wp_reg = Wp_cls + 98304;

  dim3 g0(96, 2);
  wpack_kernel<<<g0, 256, 0, stream>>>(W_cls, W_reg, Wp_cls, Wp_reg);

  dim3 g1(500, 2);
  qkv_norm_kernel<<<g1, 256, 0, stream>>>(x_cls, x_reg, Wp_cls, Wp_reg, qc_h,
                                          qr_h, kc_h, kr_h, vn_h, v_rm, v_h);

  float* out_x = (float*)d_out;                  // [2000, 512]
  float* out_sim = out_x + (size_t)N_TOK * 512;  // [2000, 2000]
  attn20_kernel<<<1000, 256, 0, stream>>>(qc_h, qr_h, kc_h, kr_h, vn_h, v_rm,
                                          v_h, out_x, out_sim);
}

// Round 21
// 295.111 us; speedup vs baseline: 1.0228x; 1.0228x over previous
//
#include <hip/hip_runtime.h>
#include <math.h>

#define N_TOK 2000
#define NH 8
#define HD 32
#define SCALE 25.0f
#define SIM_TH 0.75f
#define EPSF 1e-8f
#define NSLOT 8   // ceil(2000/256)
#define NTAIL 208 // valid lanes in slot 7: 2000 - 7*256
#define SPAD 2048 // padded s_attn stride

typedef _Float16 half2_t __attribute__((ext_vector_type(2)));

__device__ __forceinline__ unsigned rflu(unsigned u) {
  return (unsigned)__builtin_amdgcn_readfirstlane((int)u);
}
__device__ __forceinline__ half2_t u2h(unsigned u) {
  return __builtin_bit_cast(half2_t, u);
}
__device__ __forceinline__ unsigned h2u(half2_t h) {
  return __builtin_bit_cast(unsigned, h);
}

// f32 += f16x2 . f16x2 (v_dot2_f32_f16; products exact, fp32 accumulate)
__device__ __forceinline__ float fdot2f(unsigned a, unsigned b, float c) {
#if __has_builtin(__builtin_amdgcn_fdot2)
  return __builtin_amdgcn_fdot2(u2h(a), u2h(b), c, false);
#else
  const half2_t ha = u2h(a), hb = u2h(b);
  return c + (float)ha.x * (float)hb.x + (float)ha.y * (float)hb.y;
#endif
}

__device__ __forceinline__ float block_max256(float v, float* red) {
#pragma unroll
  for (int off = 32; off > 0; off >>= 1) v = fmaxf(v, __shfl_xor(v, off, 64));
  __syncthreads();
  if ((threadIdx.x & 63) == 0) red[threadIdx.x >> 6] = v;
  __syncthreads();
  return fmaxf(fmaxf(red[0], red[1]), fmaxf(red[2], red[3]));
}
__device__ __forceinline__ float block_sum256(float v, float* red) {
#pragma unroll
  for (int off = 32; off > 0; off >>= 1) v += __shfl_xor(v, off, 64);
  __syncthreads();
  if ((threadIdx.x & 63) == 0) red[threadIdx.x >> 6] = v;
  __syncthreads();
  return (red[0] + red[1]) + (red[2] + red[3]);
}
// one packed block reduction for 4 sums (2 syncs total instead of 8)
__device__ __forceinline__ void block_sum4(float* v, float* red16) {
#pragma unroll
  for (int off = 32; off > 0; off >>= 1) {
#pragma unroll
    for (int q = 0; q < 4; q++) v[q] += __shfl_xor(v[q], off, 64);
  }
  __syncthreads();
  const int wid = threadIdx.x >> 6;
  if ((threadIdx.x & 63) == 0) {
#pragma unroll
    for (int q = 0; q < 4; q++) red16[wid * 4 + q] = v[q];
  }
  __syncthreads();
#pragma unroll
  for (int q = 0; q < 4; q++) {
    v[q] = (red16[q] + red16[4 + q]) + (red16[8 + q] + red16[12 + q]);
  }
}

// load a query pair's packed-f16 row into uniform uints (SGPRs)
#define LOAD_QPAIR(BUF)                                                   \
  {                                                                       \
    const uint4* __restrict__ qb = (const uint4*)(BUF) + (size_t)h * 4 * N_TOK; \
    _Pragma("unroll") for (int gg = 0; gg < 4; gg++) {                    \
      const uint4 a0 = qb[gg * N_TOK + i0];                               \
      const uint4 a1 = qb[gg * N_TOK + i1];                               \
      qp0[4 * gg + 0] = rflu(a0.x); qp0[4 * gg + 1] = rflu(a0.y);         \
      qp0[4 * gg + 2] = rflu(a0.z); qp0[4 * gg + 3] = rflu(a0.w);         \
      qp1[4 * gg + 0] = rflu(a1.x); qp1[4 * gg + 1] = rflu(a1.y);         \
      qp1[4 * gg + 2] = rflu(a1.z); qp1[4 * gg + 3] = rflu(a1.w);         \
    }                                                                     \
  }

// ---------------------------------------------------------------------------
// Kernel 0: pack W fp32 [256][768] into f16 pair-quads Wq[k/8][768].
// grid = (96, 2), block = 256
// ---------------------------------------------------------------------------
__global__ __launch_bounds__(256) void wpack_kernel(
    const float* __restrict__ W_cls, const float* __restrict__ W_reg,
    unsigned* __restrict__ Wp_cls, unsigned* __restrict__ Wp_reg) {
  const int idx = blockIdx.x * 256 + threadIdx.x;
  const int kq = idx / 768, c = idx % 768;
  const float* __restrict__ W = blockIdx.y ? W_reg : W_cls;
  uint4* __restrict__ Wq = (uint4*)(blockIdx.y ? Wp_reg : Wp_cls);
  uint4 o;
  o.x = h2u((half2_t){(_Float16)W[(8 * kq + 0) * 768 + c],
                      (_Float16)W[(8 * kq + 1) * 768 + c]});
  o.y = h2u((half2_t){(_Float16)W[(8 * kq + 2) * 768 + c],
                      (_Float16)W[(8 * kq + 3) * 768 + c]});
  o.z = h2u((half2_t){(_Float16)W[(8 * kq + 4) * 768 + c],
                      (_Float16)W[(8 * kq + 5) * 768 + c]});
  o.w = h2u((half2_t){(_Float16)W[(8 * kq + 6) * 768 + c],
                      (_Float16)W[(8 * kq + 7) * 768 + c]});
  Wq[idx] = o;
}

// ---------------------------------------------------------------------------
// Kernel 1: QKV projection via f16 W + fdot2, 4 rows/block (measured best).
// grid = (500, 2), block = 256
// ---------------------------------------------------------------------------
__global__ __launch_bounds__(256) void qkv_norm_kernel(
    const float* __restrict__ x_cls, const float* __restrict__ x_reg,
    const unsigned* __restrict__ Wp_cls, const unsigned* __restrict__ Wp_reg,
    _Float16* __restrict__ qc_h, _Float16* __restrict__ qr_h,
    _Float16* __restrict__ kc_h, _Float16* __restrict__ kr_h,
    _Float16* __restrict__ vn_h, float* __restrict__ v_rm,
    _Float16* __restrict__ v_h) {
  __shared__ unsigned xs_p[4][128];
  __shared__ float res[4][768];
  __shared__ float inv_norm[96];

  const int n0 = blockIdx.x * 4;
  const int which = blockIdx.y;
  const int tid = threadIdx.x;
  const float* __restrict__ x = which ? x_reg : x_cls;
  const uint4* __restrict__ Wq = (const uint4*)(which ? Wp_reg : Wp_cls);

  if (tid < 128) {
#pragma unroll
    for (int r = 0; r < 4; r++) {
      const float2 xv = ((const float2*)x)[(size_t)(n0 + r) * 128 + tid];
      xs_p[r][tid] = h2u((half2_t){(_Float16)xv.x, (_Float16)xv.y});
    }
  }
  __syncthreads();

  float acc[4][3];
#pragma unroll
  for (int r = 0; r < 4; r++) acc[r][0] = acc[r][1] = acc[r][2] = 0.f;

#pragma unroll 2
  for (int kq = 0; kq < 32; kq++) {
    const uint4 w0 = Wq[kq * 768 + tid];
    const uint4 w1 = Wq[kq * 768 + tid + 256];
    const uint4 w2 = Wq[kq * 768 + tid + 512];
#pragma unroll
    for (int r = 0; r < 4; r++) {
      const uint4 xp = *(const uint4*)&xs_p[r][kq * 4];
      acc[r][0] = fdot2f(w0.x, xp.x, acc[r][0]);
      acc[r][0] = fdot2f(w0.y, xp.y, acc[r][0]);
      acc[r][0] = fdot2f(w0.z, xp.z, acc[r][0]);
      acc[r][0] = fdot2f(w0.w, xp.w, acc[r][0]);
      acc[r][1] = fdot2f(w1.x, xp.x, acc[r][1]);
      acc[r][1] = fdot2f(w1.y, xp.y, acc[r][1]);
      acc[r][1] = fdot2f(w1.z, xp.z, acc[r][1]);
      acc[r][1] = fdot2f(w1.w, xp.w, acc[r][1]);
      acc[r][2] = fdot2f(w2.x, xp.x, acc[r][2]);
      acc[r][2] = fdot2f(w2.y, xp.y, acc[r][2]);
      acc[r][2] = fdot2f(w2.z, xp.z, acc[r][2]);
      acc[r][2] = fdot2f(w2.w, xp.w, acc[r][2]);
    }
  }
#pragma unroll
  for (int r = 0; r < 4; r++) {
    res[r][tid] = acc[r][0];
    res[r][tid + 256] = acc[r][1];
    res[r][tid + 512] = acc[r][2];
  }
  __syncthreads();

  if (tid < 96) {
    const int r = tid / 24, grp = tid % 24;
    float ss = 0.f;
#pragma unroll
    for (int d = 0; d < HD; d++) {
      const float v = res[r][grp * 32 + d];
      ss += v * v;
    }
    inv_norm[tid] = 1.0f / (sqrtf(ss) + EPSF);
  }
  __syncthreads();

#pragma unroll
  for (int j = 0; j < 3; j++) {
    const int c = tid + j * 256;
    const int qkv = c >> 8, grp = c >> 5;
    const int h = grp & 7, d = c & 31;
    const int gg = d >> 3, dd = d & 7;
#pragma unroll
    for (int r = 0; r < 4; r++) {
      const int n = n0 + r;
      const float val = res[r][c];
      const float nval = val * inv_norm[r * 24 + grp];
      const size_t fi = ((size_t)(h * 4 + gg) * N_TOK + n) * 8 + dd;
      if (qkv == 0) {
        (which ? qr_h : qc_h)[fi] = (_Float16)nval;
      } else if (qkv == 1) {
        (which ? kr_h : kc_h)[fi] = (_Float16)nval;
      } else if (which == 0) {
        v_rm[(h * N_TOK + n) * HD + d] = val;
        vn_h[fi] = (_Float16)nval;
        v_h[((size_t)h * N_TOK + n) * HD + d] = (_Float16)val;
      }
    }
  }
}

// ---------------------------------------------------------------------------
// Kernel 2: session-best structure (r19, measured 230us): TQ=2, f16 score
// streams with 3-stage pipelined sweeps, deferred normalization (one packed
// block_sum4 per head), f16 row-major V PV with rotated conflict-free LDS
// reads, fp32 er, register sim/raw slots, XCD head rotation.
// Plateau evidence: waves/CU pinned ~7 and L2 stream rate pinned ~29 B/cyc/CU
// across r13-r20; fusion (r18), deeper prefetch (r19), dual streams (r20)
// all neutral-to-regressive. grid = 1000, block = 256
// ---------------------------------------------------------------------------
__global__ __launch_bounds__(256) void attn21_kernel(
    const _Float16* __restrict__ qc_h, const _Float16* __restrict__ qr_h,
    const _Float16* __restrict__ kc_h, const _Float16* __restrict__ kr_h,
    const _Float16* __restrict__ vn_h, const float* __restrict__ v_rm,
    const _Float16* __restrict__ v_h,
    float* __restrict__ out_x, float* __restrict__ out_sim) {
  __shared__ float s_attn[2][SPAD];  // 16 KB; tails stay 0 for PV
  __shared__ float s_union[4608];    // 18.4 KB: er[2][2000] / part (str 17)
  __shared__ float red[16];

  float* __restrict__ s_er = s_union;
  float* __restrict__ part = s_union;  // [64 slices][4 g2] units of 17 floats

  const int tid = threadIdx.x;
  const int i0 = blockIdx.x * 2;
  const int i1 = i0 + 1;
  const int bs = (i0 / 10) * 10;  // i0 even -> i0,i1 share the same decade

  float sim0[NSLOT], sim1[NSLOT], raw0[NSLOT], raw1[NSLOT];
#pragma unroll
  for (int t = 0; t < NSLOT; t++) {
    sim0[t] = 0.f; sim1[t] = 0.f; raw0[t] = 0.f; raw1[t] = 0.f;
  }
  if (tid < SPAD - N_TOK) {
    s_attn[0][N_TOK + tid] = 0.f;
    s_attn[1][N_TOK + tid] = 0.f;
  }
  __syncthreads();

  unsigned qp0[16], qp1[16];  // packed f16 query pairs, wave-uniform -> SGPR

  // 3-stage pipelined sweep: loads for t+2 in flight during t's compute.
  auto sweep = [&](const uint4* __restrict__ kt4, auto&& emit) {
    uint4 ka[4], kb[4];
#pragma unroll
    for (int g_ = 0; g_ < 4; g_++) ka[g_] = kt4[g_ * N_TOK + tid];  // t=0
    {
      const int m1 = tid + 256;  // t=1 always valid (t=1 < 7)
#pragma unroll
      for (int g_ = 0; g_ < 4; g_++) kb[g_] = kt4[g_ * N_TOK + m1];
    }
#pragma unroll
    for (int t = 0; t < NSLOT; t++) {
      uint4 kc_[4];
      if (t < NSLOT - 2) {  // prefetch t+2
        const int m2 = tid + 256 * (t + 2);
        const bool v2 = (t + 2 < 7) || (tid < NTAIL);
        const int mc2 = v2 ? m2 : (N_TOK - 1);
#pragma unroll
        for (int g_ = 0; g_ < 4; g_++) kc_[g_] = kt4[g_ * N_TOK + mc2];
      }
      float d0 = 0.f, d1 = 0.f;
#pragma unroll
      for (int g_ = 0; g_ < 4; g_++) {
        d0 = fdot2f(ka[g_].x, qp0[4 * g_ + 0], d0);
        d0 = fdot2f(ka[g_].y, qp0[4 * g_ + 1], d0);
        d0 = fdot2f(ka[g_].z, qp0[4 * g_ + 2], d0);
        d0 = fdot2f(ka[g_].w, qp0[4 * g_ + 3], d0);
        d1 = fdot2f(ka[g_].x, qp1[4 * g_ + 0], d1);
        d1 = fdot2f(ka[g_].y, qp1[4 * g_ + 1], d1);
        d1 = fdot2f(ka[g_].z, qp1[4 * g_ + 2], d1);
        d1 = fdot2f(ka[g_].w, qp1[4 * g_ + 3], d1);
      }
      emit(t, d0, d1);
#pragma unroll
      for (int g_ = 0; g_ < 4; g_++) {
        ka[g_] = kb[g_];
        kb[g_] = kc_[g_];
      }
    }
  };

  for (int hh = 0; hh < NH; hh++) {
    const int h = (blockIdx.x + hh) & 7;  // XCD-local head schedule

    float sums[4] = {0.f, 0.f, 0.f, 0.f};  // ls0, ls1, lr0, lr1

    // ===== phase C: cls scores -> e = exp(s-25) -> s_attn (unnormalized) ===
    LOAD_QPAIR(qc_h);
    sweep((const uint4*)kc_h + (size_t)h * 4 * N_TOK,
          [&](int t, float d0, float d1) {
            const int m = tid + 256 * t;
            const bool valid = (t < 7) || (tid < NTAIL);
            const float e0 = valid ? __expf(d0 * SCALE - SCALE) : 0.f;
            const float e1 = valid ? __expf(d1 * SCALE - SCALE) : 0.f;
            sums[0] += e0; sums[1] += e1;
            if (valid) {
              s_attn[0][m] = e0;
              s_attn[1][m] = e1;
            }
          });

    // ===== phase R: reg scores -> s_er — NO reduction between phases =====
    LOAD_QPAIR(qr_h);
    sweep((const uint4*)kr_h + (size_t)h * 4 * N_TOK,
          [&](int t, float d0, float d1) {
            const int m = tid + 256 * t;
            const bool valid = (t < 7) || (tid < NTAIL);
            const float e0 = valid ? __expf(d0 * SCALE - SCALE) : 0.f;
            const float e1 = valid ? __expf(d1 * SCALE - SCALE) : 0.f;
            sums[2] += e0; sums[3] += e1;
            if (valid) {
              s_er[m] = e0;
              s_er[N_TOK + m] = e1;
            }
          });

    // ===== ONE packed reduction for all 4 softmax sums =====
    block_sum4(sums, red);
    const float n0c = 0.5f / sums[0], n1c = 0.5f / sums[1];
    const float n0r = 0.5f / sums[2], n1r = 0.5f / sums[3];

    // ===== combine, mask, sim += =====
#pragma unroll
    for (int t = 0; t < NSLOT; t++) {
      const int m = tid + 256 * t;
      if ((t < 7) || (tid < NTAIL)) {
        float a0 = s_attn[0][m] * n0c + s_er[m] * n0r;
        float a1 = s_attn[1][m] * n1c + s_er[N_TOK + m] * n1r;
        if (m >= bs && m < bs + 9) {
          if (m != i0) a0 = 0.f;
          if (m != i1) a1 = 0.f;
        }
        s_attn[0][m] = a0;
        s_attn[1][m] = a1;
        sim0[t] += a0;
        sim1[t] += a1;
      }
    }

    // ===== phase V: vn cosine -> raw += =====
    LOAD_QPAIR(vn_h);
    sweep((const uint4*)vn_h + (size_t)h * 4 * N_TOK,
          [&](int t, float d0, float d1) {
            const bool valid = (t < 7) || (tid < NTAIL);
            if (valid) { raw0[t] += d0; raw1[t] += d1; }
          });
    __syncthreads();  // s_attn final; s_er reads done -> part may reuse

    // ===== attn @ V : f16 V row-major, one uint4 = 8 d per load =====
    {
      const int g2 = tid & 3;        // d-group of 8
      const int slice = tid >> 2;    // 64 slices x 32 m
      const int m0 = slice * 32;
      float acc0[8], acc1[8];
#pragma unroll
      for (int e = 0; e < 8; e++) { acc0[e] = 0.f; acc1[e] = 0.f; }
      const _Float16* __restrict__ vb =
          v_h + (size_t)h * N_TOK * HD + g2 * 8;
#pragma unroll 2
      for (int jj = 0; jj < 8; jj++) {
        const int m = m0 + 4 * ((jj + slice) & 7);  // rotated: <=2-way LDS
        const float4 av0 = *(const float4*)&s_attn[0][m];
        const float4 av1 = *(const float4*)&s_attn[1][m];
        // m can reach 2047; av=0 there. v_h overrun (<=1.5k elems) lands in
        // the adjacent f16 plane (finite values; x0 = 0).
        uint4 vv[4];
#pragma unroll
        for (int mm = 0; mm < 4; mm++) {
          vv[mm] = *(const uint4*)(vb + (size_t)(m + mm) * HD);
        }
#pragma unroll
        for (int mm = 0; mm < 4; mm++) {
          const float a0 = ((const float*)&av0)[mm];
          const float a1 = ((const float*)&av1)[mm];
          const unsigned* vp = (const unsigned*)&vv[mm];
#pragma unroll
          for (int e = 0; e < 4; e++) {
            const half2_t hv = u2h(vp[e]);
            const float vx = (float)hv.x, vy = (float)hv.y;
            acc0[2 * e] += a0 * vx;
            acc0[2 * e + 1] += a0 * vy;
            acc1[2 * e] += a1 * vx;
            acc1[2 * e + 1] += a1 * vy;
          }
        }
      }
      __syncthreads();  // er reads in combine long done; part write safe
      float* pu = part + (size_t)(slice * 4 + g2) * 17;  // stride 17
#pragma unroll
      for (int e = 0; e < 8; e++) {
        pu[e] = acc0[e];
        pu[8 + e] = acc1[e];
      }
    }
    __syncthreads();
    if (tid < 64) {
      const int q = tid >> 5, d = tid & 31;
      const int g = d >> 3, e = d & 7;
      float s = 0.f;
#pragma unroll 8
      for (int sl = 0; sl < 64; sl++) {
        s += part[(size_t)(sl * 4 + g) * 17 + q * 8 + e];
      }
      const int irow = q ? i1 : i0;
      out_x[(size_t)irow * 512 + h * 32 + d] = s;
    } else if (tid >= 64 && tid < 128) {
      const int q = (tid - 64) >> 5, d = (tid - 64) & 31;
      const int irow = q ? i1 : i0;
      out_x[(size_t)irow * 512 + 256 + h * 32 + d] =
          v_rm[((size_t)h * N_TOK + irow) * HD + d];
    }
    __syncthreads();  // part reads done -> s_er reuse next head
  }

  // ===== sim_round2 epilogue, from registers =====
#pragma unroll
  for (int q = 0; q < 2; q++) {
    const int irow = q ? i1 : i0;
    float* __restrict__ sim = q ? sim1 : sim0;
    float* __restrict__ raw = q ? raw1 : raw0;

    float lm = -1e30f;
#pragma unroll
    for (int t = 0; t < NSLOT; t++) {
      if ((t < 7) || (tid < NTAIL)) lm = fmaxf(lm, sim[t] * 0.125f);
    }
    const float M = block_max256(lm, red);

    float ls = 0.f;
#pragma unroll
    for (int t = 0; t < NSLOT; t++) {
      const bool valid = (t < 7) || (tid < NTAIL);
      const float e = valid ? __expf(sim[t] * 0.125f - M) : 0.f;
      sim[t] = e;
      ls += e;
    }
    const float S = block_sum256(ls, red);
    const float invS = 1.0f / S;

    float lms = 0.f;
#pragma unroll
    for (int t = 0; t < NSLOT; t++) {
      const bool valid = (t < 7) || (tid < NTAIL);
      const float p = sim[t] * invS;
      const float mp = (valid && (raw[t] * 0.125f > SIM_TH)) ? p : 0.f;
      sim[t] = mp;
      lms += mp;
    }
    const float MS = block_sum256(lms, red);
    const float invMS = 1.0f / (MS + EPSF);

#pragma unroll
    for (int t = 0; t < NSLOT; t++) {
      const int m = tid + 256 * t;
      if ((t < 7) || (tid < NTAIL)) {
        out_sim[(size_t)irow * N_TOK + m] = sim[t] * invMS;
      }
    }
  }
}

// ---------------------------------------------------------------------------
extern "C" void kernel_launch(void* const* d_in, const int* in_sizes, int n_in,
                              void* d_out, int out_size, void* d_ws,
                              size_t ws_size, hipStream_t stream) {
  const float* x_cls = (const float*)d_in[0];
  const float* x_reg = (const float*)d_in[1];
  const float* W_cls = (const float*)d_in[2];
  const float* W_reg = (const float*)d_in[3];

  // ws layout: v_rm fp32, v_h f16 (NOT last: PV overrun must hit finite f16
  // data), then the score planes, then packed W.
  const size_t seg = (size_t)NH * N_TOK * HD;  // 512000 elements
  float* v_rm = (float*)d_ws;
  _Float16* v_h = (_Float16*)(v_rm + seg);
  _Float16* qc_h = v_h + seg;
  _Float16* qr_h = qc_h + seg;
  _Float16* kc_h = qr_h + seg;
  _Float16* kr_h = kc_h + seg;
  _Float16* vn_h = kr_h + seg;
  unsigned* Wp_cls = (unsigned*)(vn_h + seg);  // 98304 uints each
  unsigned* Wp_reg = Wp_cls + 98304;

  dim3 g0(96, 2);
  wpack_kernel<<<g0, 256, 0, stream>>>(W_cls, W_reg, Wp_cls, Wp_reg);

  dim3 g1(500, 2);
  qkv_norm_kernel<<<g1, 256, 0, stream>>>(x_cls, x_reg, Wp_cls, Wp_reg, qc_h,
                                          qr_h, kc_h, kr_h, vn_h, v_rm, v_h);

  float* out_x = (float*)d_out;                  // [2000, 512]
  float* out_sim = out_x + (size_t)N_TOK * 512;  // [2000, 2000]
  attn21_kernel<<<1000, 256, 0, stream>>>(qc_h, qr_h, kc_h, kr_h, vn_h, v_rm,
                                          v_h, out_x, out_sim);
}